// Round 5
// baseline (57.980 us; speedup 1.0000x reference)
//
#include <hip/hip_runtime.h>

#define HID 2048

typedef __attribute__((ext_vector_type(4))) float f32x4;

__device__ __forceinline__ float sigmoidf_(float x) {
    return 1.0f / (1.0f + __expf(-x));
}

// h0 = c0 = 0  =>  W_hh unused, f-gate dead:
//   h[j] = sigmoid(g_o) * tanh( sigmoid(g_i) * tanh(g_g) )
// One 256-thread block per output neuron j; 3 coalesced row streams + x.
template <int K>
__device__ __forceinline__ float neuron_h(
    const float* __restrict__ W,
    const float* __restrict__ b_ih,
    const float* __restrict__ b_hh,
    const float* __restrict__ x,
    float (*red)[4])
{
    const int t    = threadIdx.x;
    const int lane = t & 63;
    const int wv   = t >> 6;
    const int j    = blockIdx.x;

    const float* ri = W + (size_t)j * K;                // i-gate row
    const float* rg = W + (size_t)(j + 2 * HID) * K;    // g-gate row
    const float* ro = W + (size_t)(j + 3 * HID) * K;    // o-gate row

    const float Bi = b_ih[j]           + b_hh[j];
    const float Bg = b_ih[j + 2 * HID] + b_hh[j + 2 * HID];
    const float Bo = b_ih[j + 3 * HID] + b_hh[j + 3 * HID];

    constexpr int U = K / 1024;       // 1 (L0) or 2 (L1/L2)
    f32x4 xv[U], wi[U], wg[U], wo[U];
    #pragma unroll
    for (int u = 0; u < U; ++u) {
        const int off = u * 1024 + t * 4;               // 16B/lane, coalesced
        xv[u] = *reinterpret_cast<const f32x4*>(x  + off);
        wi[u] = *reinterpret_cast<const f32x4*>(ri + off);
        wg[u] = *reinterpret_cast<const f32x4*>(rg + off);
        wo[u] = *reinterpret_cast<const f32x4*>(ro + off);
    }

    float ai = 0.f, ag = 0.f, ao = 0.f;
    #pragma unroll
    for (int u = 0; u < U; ++u) {
        ai = fmaf(wi[u].x, xv[u].x, ai); ai = fmaf(wi[u].y, xv[u].y, ai);
        ai = fmaf(wi[u].z, xv[u].z, ai); ai = fmaf(wi[u].w, xv[u].w, ai);
        ag = fmaf(wg[u].x, xv[u].x, ag); ag = fmaf(wg[u].y, xv[u].y, ag);
        ag = fmaf(wg[u].z, xv[u].z, ag); ag = fmaf(wg[u].w, xv[u].w, ag);
        ao = fmaf(wo[u].x, xv[u].x, ao); ao = fmaf(wo[u].y, xv[u].y, ao);
        ao = fmaf(wo[u].z, xv[u].z, ao); ao = fmaf(wo[u].w, xv[u].w, ao);
    }

    #pragma unroll
    for (int m = 32; m > 0; m >>= 1) {
        ai += __shfl_xor(ai, m, 64);
        ag += __shfl_xor(ag, m, 64);
        ao += __shfl_xor(ao, m, 64);
    }

    if (lane == 0) { red[0][wv] = ai; red[1][wv] = ag; red[2][wv] = ao; }
    __syncthreads();

    const float gi = red[0][0] + red[0][1] + red[0][2] + red[0][3] + Bi;
    const float gg = red[1][0] + red[1][1] + red[1][2] + red[1][3] + Bg;
    const float go = red[2][0] + red[2][1] + red[2][2] + red[2][3] + Bo;
    return sigmoidf_(go) * tanhf(sigmoidf_(gi) * tanhf(gg));
}

template <int K>
__global__ __launch_bounds__(256) void lstm_layer_kernel(
    const float* __restrict__ W,
    const float* __restrict__ b_ih,
    const float* __restrict__ b_hh,
    const float* __restrict__ x,
    float* __restrict__ h_out)
{
    __shared__ float red[3][4];
    const float h = neuron_h<K>(W, b_ih, b_hh, x, red);
    if (threadIdx.x == 0) h_out[blockIdx.x] = h;
}

// Final layer with fused FC: out += h[j] * fc_w[j]  (+ fc_b from block 0).
// d_out must be zeroed before this kernel (memset node on the stream).
template <int K>
__global__ __launch_bounds__(256) void lstm_final_kernel(
    const float* __restrict__ W,
    const float* __restrict__ b_ih,
    const float* __restrict__ b_hh,
    const float* __restrict__ x,
    const float* __restrict__ fc_w,   // [HID]
    const float* __restrict__ fc_b,   // [1]
    float* __restrict__ out)          // [1]
{
    __shared__ float red[3][4];
    const float h = neuron_h<K>(W, b_ih, b_hh, x, red);
    if (threadIdx.x == 0) {
        float v = h * fc_w[blockIdx.x];
        if (blockIdx.x == 0) v += fc_b[0];
        atomicAdd(out, v);            // device-scope, 2048 adds total
    }
}

extern "C" void kernel_launch(void* const* d_in, const int* in_sizes, int n_in,
                              void* d_out, int out_size, void* d_ws, size_t ws_size,
                              hipStream_t stream) {
    // setup_inputs() order (all fp32; W_hh_* dead since h0=0):
    // 0:x 1:W_ih_0 2:W_hh_0 3:b_ih_0 4:b_hh_0
    // 5:W_ih_1 6:W_hh_1 7:b_ih_1 8:b_hh_1
    // 9:W_ih_2 10:W_hh_2 11:b_ih_2 12:b_hh_2
    // 13:fc_w 14:fc_b
    const float* x    = (const float*)d_in[0];
    const float* Wih0 = (const float*)d_in[1];
    const float* bih0 = (const float*)d_in[3];
    const float* bhh0 = (const float*)d_in[4];
    const float* Wih1 = (const float*)d_in[5];
    const float* bih1 = (const float*)d_in[7];
    const float* bhh1 = (const float*)d_in[8];
    const float* Wih2 = (const float*)d_in[9];
    const float* bih2 = (const float*)d_in[11];
    const float* bhh2 = (const float*)d_in[12];
    const float* fcw  = (const float*)d_in[13];
    const float* fcb  = (const float*)d_in[14];

    float* h1 = (float*)d_ws;        // [HID] fp32
    float* h2 = h1 + HID;

    hipMemsetAsync(d_out, 0, sizeof(float), stream);   // graph-legal memset node
    lstm_layer_kernel<1024><<<HID, 256, 0, stream>>>(Wih0, bih0, bhh0, x,  h1);
    lstm_layer_kernel<2048><<<HID, 256, 0, stream>>>(Wih1, bih1, bhh1, h1, h2);
    lstm_final_kernel<2048><<<HID, 256, 0, stream>>>(Wih2, bih2, bhh2, h2,
                                                     fcw, fcb, (float*)d_out);
}

// Round 6
// 53.694 us; speedup vs baseline: 1.0798x; 1.0798x over previous
//
#include <hip/hip_runtime.h>

#define HID 2048

typedef __attribute__((ext_vector_type(4))) float f32x4;

__device__ __forceinline__ float sigmoidf_(float x) {
    return 1.0f / (1.0f + __expf(-x));
}

// h0 = c0 = 0  =>  W_hh unused, f-gate dead:
//   h[j] = sigmoid(g_o) * tanh( sigmoid(g_i) * tanh(g_g) )
// One 256-thread block per output neuron j; 3 coalesced row streams + x.
template <int K>
__device__ __forceinline__ float neuron_h(
    const float* __restrict__ W,
    const float* __restrict__ b_ih,
    const float* __restrict__ b_hh,
    const float* __restrict__ x,
    float (*red)[4])
{
    const int t    = threadIdx.x;
    const int lane = t & 63;
    const int wv   = t >> 6;
    const int j    = blockIdx.x;

    const float* ri = W + (size_t)j * K;                // i-gate row
    const float* rg = W + (size_t)(j + 2 * HID) * K;    // g-gate row
    const float* ro = W + (size_t)(j + 3 * HID) * K;    // o-gate row

    const float Bi = b_ih[j]           + b_hh[j];
    const float Bg = b_ih[j + 2 * HID] + b_hh[j + 2 * HID];
    const float Bo = b_ih[j + 3 * HID] + b_hh[j + 3 * HID];

    constexpr int U = K / 1024;       // 1 (L0) or 2 (L1/L2)
    f32x4 xv[U], wi[U], wg[U], wo[U];
    #pragma unroll
    for (int u = 0; u < U; ++u) {
        const int off = u * 1024 + t * 4;               // 16B/lane, coalesced
        xv[u] = *reinterpret_cast<const f32x4*>(x  + off);
        wi[u] = *reinterpret_cast<const f32x4*>(ri + off);
        wg[u] = *reinterpret_cast<const f32x4*>(rg + off);
        wo[u] = *reinterpret_cast<const f32x4*>(ro + off);
    }

    float ai = 0.f, ag = 0.f, ao = 0.f;
    #pragma unroll
    for (int u = 0; u < U; ++u) {
        ai = fmaf(wi[u].x, xv[u].x, ai); ai = fmaf(wi[u].y, xv[u].y, ai);
        ai = fmaf(wi[u].z, xv[u].z, ai); ai = fmaf(wi[u].w, xv[u].w, ai);
        ag = fmaf(wg[u].x, xv[u].x, ag); ag = fmaf(wg[u].y, xv[u].y, ag);
        ag = fmaf(wg[u].z, xv[u].z, ag); ag = fmaf(wg[u].w, xv[u].w, ag);
        ao = fmaf(wo[u].x, xv[u].x, ao); ao = fmaf(wo[u].y, xv[u].y, ao);
        ao = fmaf(wo[u].w, xv[u].w, ao); ao = fmaf(wo[u].z, xv[u].z, ao);
    }

    #pragma unroll
    for (int m = 32; m > 0; m >>= 1) {
        ai += __shfl_xor(ai, m, 64);
        ag += __shfl_xor(ag, m, 64);
        ao += __shfl_xor(ao, m, 64);
    }

    if (lane == 0) { red[0][wv] = ai; red[1][wv] = ag; red[2][wv] = ao; }
    __syncthreads();

    const float gi = red[0][0] + red[0][1] + red[0][2] + red[0][3] + Bi;
    const float gg = red[1][0] + red[1][1] + red[1][2] + red[1][3] + Bg;
    const float go = red[2][0] + red[2][1] + red[2][2] + red[2][3] + Bo;
    return sigmoidf_(go) * tanhf(sigmoidf_(gi) * tanhf(gg));
}

// First layer; also zeroes out[0] for the final kernel's atomics (cheap,
// ordering guaranteed by the dispatch boundary).
template <int K>
__global__ __launch_bounds__(256) void lstm_first_kernel(
    const float* __restrict__ W,
    const float* __restrict__ b_ih,
    const float* __restrict__ b_hh,
    const float* __restrict__ x,
    float* __restrict__ h_out,
    float* __restrict__ out)
{
    __shared__ float red[3][4];
    const float h = neuron_h<K>(W, b_ih, b_hh, x, red);
    if (threadIdx.x == 0) {
        h_out[blockIdx.x] = h;
        if (blockIdx.x == 0) out[0] = 0.0f;
    }
}

template <int K>
__global__ __launch_bounds__(256) void lstm_layer_kernel(
    const float* __restrict__ W,
    const float* __restrict__ b_ih,
    const float* __restrict__ b_hh,
    const float* __restrict__ x,
    float* __restrict__ h_out)
{
    __shared__ float red[3][4];
    const float h = neuron_h<K>(W, b_ih, b_hh, x, red);
    if (threadIdx.x == 0) h_out[blockIdx.x] = h;
}

// Final layer with fused FC: out += h[j] * fc_w[j]  (+ fc_b from block 0).
template <int K>
__global__ __launch_bounds__(256) void lstm_final_kernel(
    const float* __restrict__ W,
    const float* __restrict__ b_ih,
    const float* __restrict__ b_hh,
    const float* __restrict__ x,
    const float* __restrict__ fc_w,   // [HID]
    const float* __restrict__ fc_b,   // [1]
    float* __restrict__ out)          // [1]
{
    __shared__ float red[3][4];
    const float h = neuron_h<K>(W, b_ih, b_hh, x, red);
    if (threadIdx.x == 0) {
        float v = h * fc_w[blockIdx.x];
        if (blockIdx.x == 0) v += fc_b[0];
        atomicAdd(out, v);            // device-scope, 2048 adds total
    }
}

extern "C" void kernel_launch(void* const* d_in, const int* in_sizes, int n_in,
                              void* d_out, int out_size, void* d_ws, size_t ws_size,
                              hipStream_t stream) {
    // setup_inputs() order (all fp32; W_hh_* dead since h0=0):
    // 0:x 1:W_ih_0 2:W_hh_0 3:b_ih_0 4:b_hh_0
    // 5:W_ih_1 6:W_hh_1 7:b_ih_1 8:b_hh_1
    // 9:W_ih_2 10:W_hh_2 11:b_ih_2 12:b_hh_2
    // 13:fc_w 14:fc_b
    const float* x    = (const float*)d_in[0];
    const float* Wih0 = (const float*)d_in[1];
    const float* bih0 = (const float*)d_in[3];
    const float* bhh0 = (const float*)d_in[4];
    const float* Wih1 = (const float*)d_in[5];
    const float* bih1 = (const float*)d_in[7];
    const float* bhh1 = (const float*)d_in[8];
    const float* Wih2 = (const float*)d_in[9];
    const float* bih2 = (const float*)d_in[11];
    const float* bhh2 = (const float*)d_in[12];
    const float* fcw  = (const float*)d_in[13];
    const float* fcb  = (const float*)d_in[14];

    float* h1 = (float*)d_ws;        // [HID] fp32
    float* h2 = h1 + HID;
    float* out = (float*)d_out;

    lstm_first_kernel<1024><<<HID, 256, 0, stream>>>(Wih0, bih0, bhh0, x,  h1, out);
    lstm_layer_kernel<2048><<<HID, 256, 0, stream>>>(Wih1, bih1, bhh1, h1, h2);
    lstm_final_kernel<2048><<<HID, 256, 0, stream>>>(Wih2, bih2, bhh2, h2,
                                                     fcw, fcb, out);
}